// Round 13
// baseline (37.613 us; speedup 1.0000x reference)
//
#include <hip/hip_runtime.h>
#include <math.h>

#define NPTS   4096
#define BATCH  8
#define BLOCK  256                    // 4 waves
#define NSPLIT 8
#define NTPB   (NPTS / 16 / NSPLIT)   // 32 n-tiles per block scan
#define MPB    256                    // m's per block (4 waves x 64)
#define MBLK   (NPTS / MPB)           // 16
#define R      4                      // 16-row m-tiles per wave
#define PPS    (BATCH * NPTS)         // points per side = 32768

typedef __attribute__((ext_vector_type(8))) short bf16x8;
typedef __attribute__((ext_vector_type(4))) float f32x4;

static __device__ __forceinline__ unsigned short bft(float v) {
  return (unsigned short)(__float_as_uint(v) >> 16);   // truncating f32->bf16
}
static __device__ __forceinline__ float bfhi(float v) {
  return __uint_as_float(__float_as_uint(v) & 0xFFFF0000u);
}

// Prep: per point, build its 32-bf16 K-column (fragment source) + init
// the atomicMin buffers and out. A-side (y): k0-2=yh, k3-5=yh, k6-8=yl,
// k9-10=|y|^2(h,l), k11-12=1. B-side (x): k0-2=(-2x)h, k3-5=(-2x)l,
// k6-8=(-2x)h, k9-10=1, k11-12=|x|^2(h,l). MFMA dot over k then gives
// d2 = |y|^2 + |x|^2 - 2 x.y with only the (yl*(-2x)l) term dropped.
__global__ __launch_bounds__(256) void prep_kernel(
    const float* __restrict__ x, const float* __restrict__ y,
    unsigned short* __restrict__ acol, unsigned short* __restrict__ bcol,
    unsigned int* __restrict__ minbuf, float* __restrict__ out) {
  const int tid = blockIdx.x * 256 + threadIdx.x;     // 0..65535
  minbuf[tid] = 0x7F800000u;                          // +inf bits (uint key)
  if (tid == 0) out[0] = 0.0f;

  const int side = tid >> 15;                         // 0: A (y), 1: B (x)
  const int idx  = tid & (PPS - 1);
  const float* p = (side ? x : y) + 3 * (size_t)idx;
  const float vx = p[0], vy = p[1], vz = p[2];
  const float s2 = vx * vx + vy * vy + vz * vz;
  const unsigned short ONE = bft(1.0f);

  unsigned short k[32];
#pragma unroll
  for (int i = 0; i < 32; ++i) k[i] = 0;

  if (side == 0) {
    k[0] = bft(vx); k[1] = bft(vy); k[2] = bft(vz);
    k[3] = k[0];    k[4] = k[1];    k[5] = k[2];
    k[6] = bft(vx - bfhi(vx)); k[7] = bft(vy - bfhi(vy)); k[8] = bft(vz - bfhi(vz));
    k[9] = bft(s2); k[10] = bft(s2 - bfhi(s2));
    k[11] = ONE; k[12] = ONE;
  } else {
    const float tx = -2.f * vx, ty = -2.f * vy, tz = -2.f * vz;
    k[0] = bft(tx); k[1] = bft(ty); k[2] = bft(tz);
    k[3] = bft(tx - bfhi(tx)); k[4] = bft(ty - bfhi(ty)); k[5] = bft(tz - bfhi(tz));
    k[6] = k[0]; k[7] = k[1]; k[8] = k[2];
    k[9] = ONE; k[10] = ONE;
    k[11] = bft(s2); k[12] = bft(s2 - bfhi(s2));
  }

  unsigned int u[16];
#pragma unroll
  for (int i = 0; i < 16; ++i)
    u[i] = (unsigned int)k[2 * i] | ((unsigned int)k[2 * i + 1] << 16);
  uint4* d4 = (uint4*)((side ? bcol : acol) + (size_t)idx * 32);
  d4[0] = make_uint4(u[0], u[1], u[2], u[3]);
  d4[1] = make_uint4(u[4], u[5], u[6], u[7]);
  d4[2] = make_uint4(u[8], u[9], u[10], u[11]);
  d4[3] = make_uint4(u[12], u[13], u[14], u[15]);
}

// Main: per (m-block, n-split, batch). Wave owns 64 m's (R=4 A-frags,
// register-resident); streams 32 n-tiles; per iter: 1 B-frag dwordx4 load,
// 4 MFMAs (C=0 input -> D = d2 tile), in-loop row-min (x->y) with masked
// atomicMin, per-lane col-min accumulators (y->x) reduced in epilogue.
// C layout (m89-verified): col n = lane&15, row m_sub = (lane>>4)*4 + reg.
// A: row = lane&15, k = (lane>>4)*8+e.  B: col = lane&15, k = (lane>>4)*8+e.
__global__ __launch_bounds__(BLOCK) void mfma_min_kernel(
    const unsigned short* __restrict__ acol,
    const unsigned short* __restrict__ bcol,
    unsigned int* __restrict__ rowmin, unsigned int* __restrict__ colmin) {
  const int mb = blockIdx.x, ns = blockIdx.y, b = blockIdx.z;
  const int lane = threadIdx.x & 63;
  const int li = lane & 15, lg = lane >> 4;
  const int w  = threadIdx.x >> 6;
  const int mwave = mb * MPB + w * 64;

  bf16x8 af[R];
#pragma unroll
  for (int f = 0; f < R; ++f) {
    const size_t m = (size_t)b * NPTS + mwave + f * 16 + li;
    af[f] = *(const bf16x8*)(acol + m * 32 + lg * 8);
  }

  const f32x4 zf = {0.f, 0.f, 0.f, 0.f};
  f32x4 cac0 = {3.4e38f, 3.4e38f, 3.4e38f, 3.4e38f};
  f32x4 cac1 = cac0, cac2 = cac0, cac3 = cac0;

  unsigned int* rowp = rowmin + (size_t)b * NPTS;

#pragma unroll 2
  for (int it = 0; it < NTPB; ++it) {
    const int nt = ns * NTPB + it;
    const size_t n = (size_t)b * NPTS + nt * 16 + li;
    const bf16x8 bfr = *(const bf16x8*)(bcol + n * 32 + lg * 8);

    const f32x4 c0 = __builtin_amdgcn_mfma_f32_16x16x32_bf16(af[0], bfr, zf, 0, 0, 0);
    const f32x4 c1 = __builtin_amdgcn_mfma_f32_16x16x32_bf16(af[1], bfr, zf, 0, 0, 0);
    const f32x4 c2 = __builtin_amdgcn_mfma_f32_16x16x32_bf16(af[2], bfr, zf, 0, 0, 0);
    const f32x4 c3 = __builtin_amdgcn_mfma_f32_16x16x32_bf16(af[3], bfr, zf, 0, 0, 0);

    // col-min accumulators (y->x): per-lane running min over n
    cac0.x = fminf(cac0.x, c0.x); cac0.y = fminf(cac0.y, c0.y);
    cac0.z = fminf(cac0.z, c0.z); cac0.w = fminf(cac0.w, c0.w);
    cac1.x = fminf(cac1.x, c1.x); cac1.y = fminf(cac1.y, c1.y);
    cac1.z = fminf(cac1.z, c1.z); cac1.w = fminf(cac1.w, c1.w);
    cac2.x = fminf(cac2.x, c2.x); cac2.y = fminf(cac2.y, c2.y);
    cac2.z = fminf(cac2.z, c2.z); cac2.w = fminf(cac2.w, c2.w);
    cac3.x = fminf(cac3.x, c3.x); cac3.y = fminf(cac3.y, c3.y);
    cac3.z = fminf(cac3.z, c3.z); cac3.w = fminf(cac3.w, c3.w);

    // row-min (x->y): min over this wave's 64 m's for the 16 n's
    const float a0 = fminf(fminf(c0.x, c0.y), fminf(c0.z, c0.w));
    const float a1 = fminf(fminf(c1.x, c1.y), fminf(c1.z, c1.w));
    const float a2 = fminf(fminf(c2.x, c2.y), fminf(c2.z, c2.w));
    const float a3 = fminf(fminf(c3.x, c3.y), fminf(c3.z, c3.w));
    float v = fminf(fminf(a0, a1), fminf(a2, a3));
    v = fminf(v, __shfl_xor(v, 16));
    v = fminf(v, __shfl_xor(v, 32));
    const unsigned int key = __float_as_uint(fmaxf(v, 0.0f));
    if (lane < 16) atomicMin(&rowp[nt * 16 + lane], key);
  }

  // col-min epilogue: reduce each (f, reg) across the 16 lanes of its group
  unsigned int* colp = colmin + (size_t)b * NPTS;
  f32x4 cc[R] = {cac0, cac1, cac2, cac3};
#pragma unroll
  for (int f = 0; f < R; ++f) {
#pragma unroll
    for (int r = 0; r < 4; ++r) {
      float v = cc[f][r];
      v = fminf(v, __shfl_xor(v, 1));
      v = fminf(v, __shfl_xor(v, 2));
      v = fminf(v, __shfl_xor(v, 4));
      v = fminf(v, __shfl_xor(v, 8));
      if (li == 0)
        atomicMin(&colp[mwave + f * 16 + lg * 4 + r],
                  __float_as_uint(fmaxf(v, 0.0f)));
    }
  }
}

// Reduce: one block per batch; max over rowmin+colmin keys (uint order ==
// float order for non-neg), sqrt, mean via atomicAdd.
__global__ __launch_bounds__(256) void reduce_kernel(
    const unsigned int* __restrict__ minbuf, float* __restrict__ out) {
  const int b = blockIdx.x;
  const uint4* rm = (const uint4*)(minbuf + (size_t)b * NPTS);
  const uint4* cm = (const uint4*)(minbuf + (size_t)PPS + (size_t)b * NPTS);
  unsigned int mx = 0u;
  for (int i = threadIdx.x; i < NPTS / 4; i += 256) {
    const uint4 a = rm[i], c = cm[i];
    mx = max(mx, max(max(a.x, a.y), max(a.z, a.w)));
    mx = max(mx, max(max(c.x, c.y), max(c.z, c.w)));
  }
  for (int off = 32; off > 0; off >>= 1)
    mx = max(mx, (unsigned int)__shfl_down(mx, off));

  __shared__ unsigned int wv[4];
  if ((threadIdx.x & 63) == 0) wv[threadIdx.x >> 6] = mx;
  __syncthreads();
  if (threadIdx.x == 0) {
    const unsigned int m = max(max(wv[0], wv[1]), max(wv[2], wv[3]));
    atomicAdd(out, sqrtf(__uint_as_float(m)) * (1.0f / BATCH));
  }
}

extern "C" void kernel_launch(void* const* d_in, const int* in_sizes, int n_in,
                              void* d_out, int out_size, void* d_ws, size_t ws_size,
                              hipStream_t stream) {
  const float* x = (const float*)d_in[0];
  const float* y = (const float*)d_in[1];
  unsigned short* acol = (unsigned short*)d_ws;                 // 2 MB
  unsigned short* bcol = acol + (size_t)PPS * 32;               // 2 MB
  unsigned int* minbuf = (unsigned int*)(bcol + (size_t)PPS * 32); // 256 KB
  float* out = (float*)d_out;

  prep_kernel<<<(2 * PPS) / 256, 256, 0, stream>>>(x, y, acol, bcol, minbuf, out);
  mfma_min_kernel<<<dim3(MBLK, NSPLIT, BATCH), BLOCK, 0, stream>>>(
      acol, bcol, minbuf, minbuf + PPS);
  reduce_kernel<<<BATCH, 256, 0, stream>>>(minbuf, out);
}